// Round 3
// baseline (151.596 us; speedup 1.0000x reference)
//
#include <hip/hip_runtime.h>

// RNNAdder round 3: B=4096, T=128, HID=64, VOCAB=10.
// 512 WGs x 256 thr (M=8 half-tiles -> 2 WGs/CU = 2 waves/SIMD for latency
// hiding). Wave w owns hidden cols w*16..w*16+15 (N-split 4).
// Per step (one barrier):
//   x = h_hi @ Whh (2 MFMA) + (h_lo @ Whh)/2048 (2 MFMA) + PP[v1*10+v2][n]
//   h = tanh(x); store h as separate f16 hi + f16 residual*2048 LDS arrays
//   (row stride 144 B: 16B-aligned b128 A-reads, balanced banks, no perms).
// xp folded via precombined PP table (100x64, stride 68 dwords) - VALU adds.
// Output projection: wave w projects h(t) when (t&7)>>1 == w, reading the
// just-published slot after the barrier (no extra barrier needed).
// Rows 8..15 of each half-tile compute bounded garbage (mirrors of 0..7).

typedef _Float16 half8 __attribute__((ext_vector_type(8)));
typedef float floatx4 __attribute__((ext_vector_type(4)));

#define MFMA16(A, B, C) __builtin_amdgcn_mfma_f32_16x16x32_f16((A), (B), (C), 0, 0, 0)

__global__ __launch_bounds__(256)
void rnn_mfma3(const int* __restrict__ num1, const int* __restrict__ num2,
               const float* __restrict__ E, const float* __restrict__ Wxh,
               const float* __restrict__ Whh, const float* __restrict__ bias,
               const float* __restrict__ Wd, const float* __restrict__ bd,
               float* __restrict__ out)
{
    __shared__ __align__(16) float    PP[100 * 68];     // PP[v1*10+v2][n], 27.2 KB
    __shared__ __align__(16) _Float16 Hhi[2][16][72];   // h hi, row 144 B, 4.6 KB
    __shared__ __align__(16) _Float16 Hlo[2][16][72];   // h residual*2048, 4.6 KB
    __shared__ int cmbp[128 * 2];                       // packed cmb bytes [t][m/4]

    const int tid  = threadIdx.x;
    const int w    = tid >> 6;        // wave = N-block
    const int lane = tid & 63;
    const int c    = lane & 15;
    const int q    = lane >> 4;
    const int g    = blockIdx.x;      // group of 8 sequences
    const int n    = w * 16 + c;      // this lane's hidden column

    // ---- staging: P1 (bias folded) / P2 into LDS scratch overlaid on Hhi/Hlo
    float* P1 = (float*)&Hhi[0][0][0];    // 640 floats (fits in 4608 B)
    float* P2 = (float*)&Hlo[0][0][0];
    for (int idx = tid; idx < 640; idx += 256) {
        int v = idx >> 6, jj = idx & 63;
        float s1 = bias[jj], s2 = 0.f;
        #pragma unroll
        for (int i = 0; i < 32; ++i) {
            float e = E[v * 32 + i];
            s1 = fmaf(e, Wxh[i * 64 + jj], s1);
            s2 = fmaf(e, Wxh[(32 + i) * 64 + jj], s2);
        }
        P1[idx] = s1;
        P2[idx] = s2;
    }
    __syncthreads();
    for (int idx = tid; idx < 6400; idx += 256) {
        int vv = idx >> 6, nn = idx & 63;
        PP[vv * 68 + nn] = P1[(vv / 10) * 64 + nn] + P2[(vv % 10) * 64 + nn];
    }
    __syncthreads();   // P1/P2 consumed; Hhi/Hlo reusable

    // ---- zero ring slot 1 (h_{-1} = 0) ----
    {
        int* hz = (int*)&Hhi[1][0][0];
        int* lz = (int*)&Hlo[1][0][0];
        for (int i = tid; i < 576; i += 256) { hz[i] = 0; lz[i] = 0; }
    }
    // ---- stage combined token indices as bytes ----
    {
        unsigned char* c8 = (unsigned char*)cmbp;
        for (int idx = tid; idx < 1024; idx += 256) {
            int m = idx >> 7, t = idx & 127;
            int s = g * 8 + m;
            int cmb = num1[s * 128 + t] * 10 + num2[s * 128 + t];
            c8[t * 8 + m] = (unsigned char)cmb;
        }
    }

    // ---- B-fragments straight from global (L2-cached, startup only) ----
    half8 Wf[2], Wdf[2];
    #pragma unroll
    for (int kt = 0; kt < 2; ++kt)
        #pragma unroll
        for (int j = 0; j < 8; ++j) {
            int k = kt * 32 + q * 8 + j;
            Wf[kt][j]  = (_Float16)Whh[k * 64 + n];
            Wdf[kt][j] = (c < 10) ? (_Float16)Wd[k * 10 + c] : (_Float16)0.f;
        }
    float bdv = (c < 10) ? bd[c] : 0.f;
    __syncthreads();

    const floatx4 zero4 = {0.f, 0.f, 0.f, 0.f};
    const int qh = q & 1;             // valid row-group for cmb (rows 8..15 mirror)

    for (int t = 0; t < 128; ++t) {
        const int sp = (t + 1) & 1;   // slot holding h(t-1)
        const int sc = t & 1;         // slot to write h(t)

        // A-fragments: direct half8 loads, 16B-aligned, no perms
        half8 Ah0 = *(const half8*)&Hhi[sp][c][q * 8];
        half8 Ah1 = *(const half8*)&Hhi[sp][c][32 + q * 8];
        half8 Al0 = *(const half8*)&Hlo[sp][c][q * 8];
        half8 Al1 = *(const half8*)&Hlo[sp][c][32 + q * 8];

        floatx4 C1 = MFMA16(Ah0, Wf[0], zero4);
        C1         = MFMA16(Ah1, Wf[1], C1);
        floatx4 C2 = MFMA16(Al0, Wf[0], zero4);
        C2         = MFMA16(Al1, Wf[1], C2);

        int cp = cmbp[t * 2 + qh];    // 4 cmb bytes for rows m = qh*4..qh*4+3

        #pragma unroll
        for (int r = 0; r < 4; ++r) {
            int   cmb = (cp >> (8 * r)) & 0xFF;
            float pp  = PP[cmb * 68 + n];
            float x   = fmaf(C2[r], (1.f / 2048.f), C1[r]) + pp;
            float e2  = __builtin_amdgcn_exp2f(x * 2.885390081777927f);
            float hv  = 1.f - 2.f * __builtin_amdgcn_rcpf(e2 + 1.f);
            _Float16 hh = (_Float16)hv;
            _Float16 hl = (_Float16)((hv - (float)hh) * 2048.f);
            Hhi[sc][q * 4 + r][n] = hh;
            Hlo[sc][q * 4 + r][n] = hl;
        }
        __syncthreads();

        // ---- spread-out output projection: wave w projects h(t) ----
        if (((t & 7) >> 1) == w) {
            half8 Ph0 = *(const half8*)&Hhi[sc][c][q * 8];
            half8 Ph1 = *(const half8*)&Hhi[sc][c][32 + q * 8];
            floatx4 Cp = MFMA16(Ph0, Wdf[0], zero4);
            Cp         = MFMA16(Ph1, Wdf[1], Cp);
            if (q < 2 && c < 10) {
                #pragma unroll
                for (int r = 0; r < 4; ++r) {
                    int m = q * 4 + r;
                    out[((g * 8 + m) * 128 + t) * 10 + c] = Cp[r] + bdv;
                }
            }
        }
    }
}

extern "C" void kernel_launch(void* const* d_in, const int* in_sizes, int n_in,
                              void* d_out, int out_size, void* d_ws, size_t ws_size,
                              hipStream_t stream) {
    const int*   num1 = (const int*)d_in[0];
    const int*   num2 = (const int*)d_in[1];
    const float* E    = (const float*)d_in[2];
    const float* Wxh  = (const float*)d_in[3];
    const float* Whh  = (const float*)d_in[4];
    const float* b    = (const float*)d_in[5];
    const float* Wd   = (const float*)d_in[6];
    const float* bd   = (const float*)d_in[7];
    float* out = (float*)d_out;
    rnn_mfma3<<<512, 256, 0, stream>>>(num1, num2, E, Wxh, Whh, b, Wd, bd, out);
}